// Round 2
// baseline (975.863 us; speedup 1.0000x reference)
//
#include <hip/hip_runtime.h>
#include <stdint.h>

#define D      2048
#define KSEL   512
#define CHUNKS 8     // D / (64 lanes * 4 elems)

typedef float    f4 __attribute__((ext_vector_type(4)));
typedef unsigned u4 __attribute__((ext_vector_type(4)));

// ---- wave(64) reductions ----
__device__ __forceinline__ unsigned wave_min_u(unsigned v) {
    #pragma unroll
    for (int o = 32; o > 0; o >>= 1) { unsigned t = __shfl_xor((int)v, o, 64); v = (t < v) ? t : v; }
    return v;
}
__device__ __forceinline__ unsigned wave_max_u(unsigned v) {
    #pragma unroll
    for (int o = 32; o > 0; o >>= 1) { unsigned t = __shfl_xor((int)v, o, 64); v = (t > v) ? t : v; }
    return v;
}

// ballot-based counts: v_cmp -> sgpr pair, s_bcnt on scalar pipe.
// No DS-swizzle latency chain; result is wave-uniform.
__device__ __forceinline__ int count_ge(const u4* r, unsigned p) {
    int c = 0;
    #pragma unroll
    for (int i = 0; i < CHUNKS; ++i) {
        c += (int)__popcll(__ballot(r[i][0] >= p));
        c += (int)__popcll(__ballot(r[i][1] >= p));
        c += (int)__popcll(__ballot(r[i][2] >= p));
        c += (int)__popcll(__ballot(r[i][3] >= p));
    }
    return c;
}
__device__ __forceinline__ int count_eq(const u4* r, unsigned p) {
    int c = 0;
    #pragma unroll
    for (int i = 0; i < CHUNKS; ++i) {
        c += (int)__popcll(__ballot(r[i][0] == p));
        c += (int)__popcll(__ballot(r[i][1] == p));
        c += (int)__popcll(__ballot(r[i][2] == p));
        c += (int)__popcll(__ballot(r[i][3] == p));
    }
    return c;
}
__device__ __forceinline__ unsigned min_ge(const u4* r, unsigned lo) {
    unsigned m = 0xFFFFFFFFu;
    #pragma unroll
    for (int i = 0; i < CHUNKS; ++i) {
        unsigned a;
        a = r[i][0]; if (a >= lo && a < m) m = a;
        a = r[i][1]; if (a >= lo && a < m) m = a;
        a = r[i][2]; if (a >= lo && a < m) m = a;
        a = r[i][3]; if (a >= lo && a < m) m = a;
    }
    return wave_min_u(m);
}
__device__ __forceinline__ unsigned max_in(const u4* r, unsigned lo, unsigned hi) {
    unsigned m = 0u;
    #pragma unroll
    for (int i = 0; i < CHUNKS; ++i) {
        unsigned a;
        a = r[i][0]; if (a >= lo && a <= hi && a > m) m = a;
        a = r[i][1]; if (a >= lo && a <= hi && a > m) m = a;
        a = r[i][2]; if (a >= lo && a <= hi && a > m) m = a;
        a = r[i][3]; if (a >= lo && a <= hi && a > m) m = a;
    }
    return wave_max_u(m);
}

// exact top-K threshold selection shared by both paths.
// Returns T, need2, cnteq via refs. rb must hold the row's rand bits.
__device__ __forceinline__ void select_topk(const u4* rb, unsigned& T, int& need2, int& cnteq) {
    unsigned lo = 0u, hi = 0x3F7FFFFFu;
    int cnt_lo = D, cnt_hi1 = 0;
    int it = 0;
    for (;;) {
        if (cnt_lo == KSEL) {            // top-K set is exactly {v >= lo}
            T = min_ge(rb, lo);
            cnteq = count_eq(rb, T);
            need2 = cnteq;
            break;
        }
        if (cnt_hi1 == KSEL - 1) {       // exactly one more needed: T = max in [lo,hi]
            T = max_in(rb, lo, hi);
            cnteq = count_eq(rb, T);
            need2 = 1;
            break;
        }
        if (lo == hi) {
            T = lo;
            cnteq = cnt_lo - cnt_hi1;
            need2 = KSEL - cnt_hi1;
            break;
        }
        unsigned mid;
        if (it & 1) {                    // guaranteed-progress bisection
            mid = lo + ((hi - lo + 1) >> 1);
        } else {                         // interpolation in value space (uniform dist)
            float lof = __uint_as_float(lo);
            float hif = __uint_as_float(hi + 1);
            float frac = (float)(cnt_lo - KSEL) / (float)(cnt_lo - cnt_hi1);
            float mf = lof + frac * (hif - lof);
            mid = __float_as_uint(mf);
            if (mid < lo + 1) mid = lo + 1;
            if (mid > hi)     mid = hi;
        }
        int c = count_ge(rb, mid);
        if (c >= KSEL) { lo = mid; cnt_lo = c; }
        else           { hi = mid - 1; cnt_hi1 = c; }
        ++it;
    }
}

// ---------------- Kernel A: selection -> packed 4-bit/f4 mask ----------------
// mask layout: maskw[row*64 + lane], bit (4*c + j) covers element (c*64+lane)*4 + j
__global__ __launch_bounds__(256, 8)
void BaseObservationModel_sel_kernel(
    const float* __restrict__ rand_vals, unsigned* __restrict__ maskw,
    long long n_elems)
{
    const int lane = threadIdx.x & 63;
    const long long rows = n_elems / D;
    const long long row  = (long long)blockIdx.x * 4 + (threadIdx.x >> 6);
    if (row >= rows) return;

    const u4* rp = (const u4*)(rand_vals + row * D);
    u4 rb[CHUNKS];
    #pragma unroll
    for (int i = 0; i < CHUNKS; ++i) rb[i] = __builtin_nontemporal_load(rp + i * 64 + lane);

    unsigned T; int need2, cnteq;
    select_topk(rb, T, need2, cnteq);

    const bool fast = (need2 == cnteq);  // common case: all elements == T are masked
    unsigned w = 0u;

    if (fast) {
        #pragma unroll
        for (int i = 0; i < CHUNKS; ++i) {
            const u4 rv = rb[i];
            w |= (rv[0] >= T ? 1u : 0u) << (4 * i + 0);
            w |= (rv[1] >= T ? 1u : 0u) << (4 * i + 1);
            w |= (rv[2] >= T ? 1u : 0u) << (4 * i + 2);
            w |= (rv[3] >= T ? 1u : 0u) << (4 * i + 3);
        }
    } else {
        // rare tie path: stable lower-index-first ranking of equals
        int rank_base = 0;
        #pragma unroll
        for (int i = 0; i < CHUNKS; ++i) {
            const u4 rv = rb[i];
            const bool e0 = (rv[0] == T), e1 = (rv[1] == T), e2 = (rv[2] == T), e3 = (rv[3] == T);
            int myc = (int)e0 + (int)e1 + (int)e2 + (int)e3;
            int inc = myc;
            #pragma unroll
            for (int o = 1; o < 64; o <<= 1) {
                int t = __shfl_up(inc, o, 64);
                if (lane >= o) inc += t;
            }
            int r = rank_base + inc - myc;   // exclusive prefix over lanes
            bool m0 = (rv[0] > T) || (e0 && r < need2); r += (int)e0;
            bool m1 = (rv[1] > T) || (e1 && r < need2); r += (int)e1;
            bool m2 = (rv[2] > T) || (e2 && r < need2); r += (int)e2;
            bool m3 = (rv[3] > T) || (e3 && r < need2); r += (int)e3;
            w |= (m0 ? 1u : 0u) << (4 * i + 0);
            w |= (m1 ? 1u : 0u) << (4 * i + 1);
            w |= (m2 ? 1u : 0u) << (4 * i + 2);
            w |= (m3 ? 1u : 0u) << (4 * i + 3);
            rank_base += __shfl(inc, 63, 64);
        }
    }
    maskw[(row << 6) + lane] = w;   // normal (cached) store — B reads it right after
}

// ---------------- Kernel B: pure stream apply ----------------
__global__ __launch_bounds__(256, 8)
void BaseObservationModel_apply_kernel(
    const float* __restrict__ data, const float* __restrict__ noise,
    const unsigned* __restrict__ maskw, float* __restrict__ out,
    long long n_elems)
{
    const int lane = threadIdx.x & 63;
    const long long rows = n_elems / D;
    const long long row  = (long long)blockIdx.x * 4 + (threadIdx.x >> 6);
    if (row >= rows) return;
    const long long base = row * D;

    const f4* dp = (const f4*)(data + base);
    const f4* np = (const f4*)(noise + base);
    f4* op = (f4*)(out + base);             // masked
    f4* ip = (f4*)(out + n_elems + base);   // mask_inverse

    const unsigned w = maskw[(row << 6) + lane];

    #pragma unroll
    for (int i = 0; i < CHUNKS; ++i) {
        const f4 d = __builtin_nontemporal_load(dp + i * 64 + lane);
        const f4 n = __builtin_nontemporal_load(np + i * 64 + lane);
        const unsigned b = (w >> (4 * i)) & 0xFu;
        f4 o4, i4;
        o4[0] = (b & 1u) ? 0.0f : fmaf(0.1f, n[0], d[0]);
        o4[1] = (b & 2u) ? 0.0f : fmaf(0.1f, n[1], d[1]);
        o4[2] = (b & 4u) ? 0.0f : fmaf(0.1f, n[2], d[2]);
        o4[3] = (b & 8u) ? 0.0f : fmaf(0.1f, n[3], d[3]);
        i4[0] = (b & 1u) ? 0.0f : 1.0f;
        i4[1] = (b & 2u) ? 0.0f : 1.0f;
        i4[2] = (b & 4u) ? 0.0f : 1.0f;
        i4[3] = (b & 8u) ? 0.0f : 1.0f;
        __builtin_nontemporal_store(o4, op + i * 64 + lane);
        __builtin_nontemporal_store(i4, ip + i * 64 + lane);
    }
}

// ---------------- Fallback: fused single kernel (R1 version) ----------------
__global__ __launch_bounds__(256, 6)
void BaseObservationModel_fused_kernel(
    const float* __restrict__ data, const float* __restrict__ noise,
    const float* __restrict__ rand_vals, float* __restrict__ out,
    long long n_elems)
{
    const int lane = threadIdx.x & 63;
    const long long rows = n_elems / D;
    const long long row  = (long long)blockIdx.x * 4 + (threadIdx.x >> 6);
    if (row >= rows) return;
    const long long base = row * D;

    const u4* rp = (const u4*)(rand_vals + base);
    const f4* dp = (const f4*)(data + base);
    const f4* np = (const f4*)(noise + base);
    f4* op = (f4*)(out + base);
    f4* ip = (f4*)(out + n_elems + base);

    u4 rb[CHUNKS];
    #pragma unroll
    for (int i = 0; i < CHUNKS; ++i) rb[i] = __builtin_nontemporal_load(rp + i * 64 + lane);

    unsigned T; int need2, cnteq;
    select_topk(rb, T, need2, cnteq);

    const bool fast = (need2 == cnteq);
    int rank_base = 0;

    #pragma unroll
    for (int i = 0; i < CHUNKS; ++i) {
        const f4 d = __builtin_nontemporal_load(dp + i * 64 + lane);
        const f4 n = __builtin_nontemporal_load(np + i * 64 + lane);
        const u4 rv = rb[i];
        bool m0, m1, m2, m3;
        if (fast) {
            m0 = rv[0] >= T; m1 = rv[1] >= T; m2 = rv[2] >= T; m3 = rv[3] >= T;
        } else {
            const bool e0 = (rv[0] == T), e1 = (rv[1] == T), e2 = (rv[2] == T), e3 = (rv[3] == T);
            int myc = (int)e0 + (int)e1 + (int)e2 + (int)e3;
            int inc = myc;
            #pragma unroll
            for (int o = 1; o < 64; o <<= 1) {
                int t = __shfl_up(inc, o, 64);
                if (lane >= o) inc += t;
            }
            int r = rank_base + inc - myc;
            m0 = (rv[0] > T) || (e0 && r < need2); r += (int)e0;
            m1 = (rv[1] > T) || (e1 && r < need2); r += (int)e1;
            m2 = (rv[2] > T) || (e2 && r < need2); r += (int)e2;
            m3 = (rv[3] > T) || (e3 && r < need2); r += (int)e3;
            rank_base += __shfl(inc, 63, 64);
        }
        f4 o4, i4;
        o4[0] = m0 ? 0.0f : fmaf(0.1f, n[0], d[0]);
        o4[1] = m1 ? 0.0f : fmaf(0.1f, n[1], d[1]);
        o4[2] = m2 ? 0.0f : fmaf(0.1f, n[2], d[2]);
        o4[3] = m3 ? 0.0f : fmaf(0.1f, n[3], d[3]);
        i4[0] = m0 ? 0.0f : 1.0f;
        i4[1] = m1 ? 0.0f : 1.0f;
        i4[2] = m2 ? 0.0f : 1.0f;
        i4[3] = m3 ? 0.0f : 1.0f;
        __builtin_nontemporal_store(o4, op + i * 64 + lane);
        __builtin_nontemporal_store(i4, ip + i * 64 + lane);
    }
}

extern "C" void kernel_launch(void* const* d_in, const int* in_sizes, int n_in,
                              void* d_out, int out_size, void* d_ws, size_t ws_size,
                              hipStream_t stream) {
    const float* data      = (const float*)d_in[0];
    const float* noise     = (const float*)d_in[1];
    const float* rand_vals = (const float*)d_in[2];
    float* out = (float*)d_out;
    const long long n = (long long)in_sizes[0];       // 32*1024*2048 = 67108864
    const long long rows = n / D;                     // 32768
    const int blocks = (int)((rows + 3) / 4);         // 4 waves (rows) per 256-thread block

    const size_t mask_bytes = (size_t)rows * 64 * sizeof(unsigned);  // 8 MB
    if (d_ws != nullptr && ws_size >= mask_bytes) {
        unsigned* maskw = (unsigned*)d_ws;
        BaseObservationModel_sel_kernel<<<blocks, 256, 0, stream>>>(rand_vals, maskw, n);
        BaseObservationModel_apply_kernel<<<blocks, 256, 0, stream>>>(data, noise, maskw, out, n);
    } else {
        BaseObservationModel_fused_kernel<<<blocks, 256, 0, stream>>>(
            data, noise, rand_vals, out, n);
    }
}